// Round 5
// baseline (4591.248 us; speedup 1.0000x reference)
//
#include <hip/hip_runtime.h>
#include <hip/hip_bf16.h>

#define DEV __device__ __forceinline__

namespace {
constexpr int T_ = 16;
constexpr int C_ = 64;
constexpr int H_ = 128;
constexpr int W_ = 128;
constexpr int HW_ = H_ * W_;            // 16384
constexpr long CHW_ = (long)C_ * HW_;   // 1,048,576 floats per (n,t) plane
}

struct Bil { int o00, o01, o10, o11; float w00, w01, w10, w11; };

DEV Bil make_bil(float gx, float gy) {
  float x0f = floorf(gx), y0f = floorf(gy);
  float wx = gx - x0f, wy = gy - y0f;
  int x0 = (int)x0f, y0 = (int)y0f;
  int x1 = x0 + 1, y1 = y0 + 1;
  bool vx0 = (x0 >= 0) && (x0 < W_), vx1 = (x1 >= 0) && (x1 < W_);
  bool vy0 = (y0 >= 0) && (y0 < H_), vy1 = (y1 >= 0) && (y1 < H_);
  int cx0 = min(max(x0, 0), W_ - 1), cx1 = min(max(x1, 0), W_ - 1);
  int cy0 = min(max(y0, 0), H_ - 1), cy1 = min(max(y1, 0), H_ - 1);
  Bil b;
  b.o00 = cy0 * W_ + cx0; b.o01 = cy0 * W_ + cx1;
  b.o10 = cy1 * W_ + cx0; b.o11 = cy1 * W_ + cx1;
  b.w00 = (vx0 && vy0) ? (1.f - wx) * (1.f - wy) : 0.f;
  b.w01 = (vx1 && vy0) ? wx * (1.f - wy) : 0.f;
  b.w10 = (vx0 && vy1) ? (1.f - wx) * wy : 0.f;
  b.w11 = (vx1 && vy1) ? wx * wy : 0.f;
  return b;
}

// Kernel 1: flow-warp (a2, a1) + concat x + 1x1 conv (192->64), all fp32.
// v6: v5's co-quarter split repeated every pixel's 128-plane bilinear
// gather 4x. Fix: 32 co per thread (co-half split), with each section's 64
// warped values buffered in statically-indexed vbuf[64] (fully unrolled ->
// registers, no scratch). Gather instrs and address-VALU halve; FMA total
// unchanged; weights stay block-uniform -> s_load + v_fmac v,s,v.
// Grid 512 x 128 (2 blocks/CU). Per-acc k-order (section, c0 asc, u asc)
// unchanged -> bit-identical output.
__global__ __launch_bounds__(128) void warp_fc_k(
    const float* __restrict__ flows,    // (N,T,2,HW)
    const float* __restrict__ xfeats,   // pristine feats base (x_t source)
    const float* __restrict__ y1p, long y1s,   // y1 planes, n-stride (floats)
    const float* __restrict__ y2p, long y2s,   // y2 planes
    const float* __restrict__ Wfc, const float* __restrict__ bfc,
    int f1t, int f2t, int t,
    float* __restrict__ ifp, long ifs) {       // infeat out, n-stride
  const int tid = threadIdx.x;               // 0..127
  const int bx  = blockIdx.x;                // 0..511
  const int n    = bx >> 8;                  // 0..1
  const int half = (bx >> 7) & 1;            // co-half 0..1
  const int p    = ((bx & 127) << 7) + tid;  // 0..16383
  const int py = p >> 7, px = p & (W_ - 1);

  float f1x = 0.f, f1y = 0.f;
  if (f1t >= 0) {
    const float* fp = flows + (long)((n * T_ + f1t) * 2) * HW_;
    f1x = fp[p];
    f1y = fp[HW_ + p];
  }
  Bil b1 = make_bil((float)px + f1x, (float)py + f1y);

  float f2cx = f1x, f2cy = f1y;   // warp of zero field is zero
  if (f2t >= 0) {
    const float* f2p = flows + (long)((n * T_ + f2t) * 2) * HW_;
    f2cx += b1.w00 * f2p[b1.o00] + b1.w01 * f2p[b1.o01] +
            b1.w10 * f2p[b1.o10] + b1.w11 * f2p[b1.o11];
    const float* f2q = f2p + HW_;
    f2cy += b1.w00 * f2q[b1.o00] + b1.w01 * f2q[b1.o01] +
            b1.w10 * f2q[b1.o10] + b1.w11 * f2q[b1.o11];
  }
  Bil b2 = make_bil((float)px + f2cx, (float)py + f2cy);

  float acc[32];
  #pragma unroll
  for (int i = 0; i < 32; i++) acc[i] = bfc[half * 32 + i];

  // this half's weight rows: Wfc[(half*32+co)*192 + k], k-contiguous
  const float* wh = Wfc + (long)(half * 32) * 192;

  float vbuf[64];   // statically indexed (all loops fully unrolled)

  // FMA block over current vbuf for k-section base KOFF (h2/co/u static).
#define FMASEC(KOFF)                                                          \
  _Pragma("unroll")                                                           \
  for (int h2 = 0; h2 < 2; ++h2) {                                            \
    _Pragma("unroll")                                                         \
    for (int c0 = 0; c0 < 64; c0 += 4) {                                      \
      _Pragma("unroll")                                                       \
      for (int co = 0; co < 16; ++co) {                                       \
        float4 w = *(const float4*)(wh + (long)(h2 * 16 + co) * 192 +         \
                                    (KOFF) + c0);                             \
        float* a = &acc[h2 * 16 + co];                                        \
        *a += w.x * vbuf[c0];                                                 \
        *a += w.y * vbuf[c0 + 1];                                             \
        *a += w.z * vbuf[c0 + 2];                                             \
        *a += w.w * vbuf[c0 + 3];                                             \
      }                                                                       \
    }                                                                         \
  }

  // k = 0..63 : a2 = warp(y2, f2c)
  {
    const float* y2b = y2p + (long)n * y2s;
    #pragma unroll
    for (int c0 = 0; c0 < 64; ++c0) {
      const float* pl = y2b + (long)c0 * HW_;
      vbuf[c0] = b2.w00 * pl[b2.o00] + b2.w01 * pl[b2.o01] +
                 b2.w10 * pl[b2.o10] + b2.w11 * pl[b2.o11];
    }
    FMASEC(0)
  }
  // k = 64..127 : a1 = warp(y1, f1)
  {
    const float* y1b = y1p + (long)n * y1s;
    #pragma unroll
    for (int c0 = 0; c0 < 64; ++c0) {
      const float* pl = y1b + (long)c0 * HW_;
      vbuf[c0] = b1.w00 * pl[b1.o00] + b1.w01 * pl[b1.o01] +
                 b1.w10 * pl[b1.o10] + b1.w11 * pl[b1.o11];
    }
    FMASEC(64)
  }
  // k = 128..191 : x = feats[:, t]
  {
    const float* xb = xfeats + (long)(n * T_ + t) * CHW_ + p;
    #pragma unroll
    for (int c0 = 0; c0 < 64; ++c0) vbuf[c0] = xb[(long)c0 * HW_];
    FMASEC(128)
  }
#undef FMASEC

  float* o = ifp + (long)n * ifs + p;
  #pragma unroll
  for (int i = 0; i < 32; i++) o[(long)(half * 32 + i) * HW_] = acc[i];
}

// 3x3 SAME conv 64->64, fp32. v6:
//   R4 model: v5 was LDS-issue bound (~33us floor): 14 LDS instr/cc/thread,
//   6 of them WEIGHT reads. Weights are wave-indexable -> make co
//   WAVE-UNIFORM so weights come from the scalar pipe (s_load; fmac v,s,v),
//   deleting all weight LDS (48KB + preload + 6 instr/cc).
//   New mapping: tile 16 rows x 32 cols; 256 thr = 4 waves; wave w owns
//   co-pair {cg*8+w, cg*8+w+4} over the WHOLE tile (readfirstlane -> SGPR);
//   lane = 2x4 px patch (prr=lane>>3 row-strip, pcc=lane&7 col-strip).
//   Per cc/thread: 8 tile b128 only -> per-CU LDS ~576cyc/cc ~= FMA issue.
//   Keeps v5's proven dbuf skeleton: issue-early global loads, compute,
//   ds_write late, ONE barrier/round; flat scalars only (no spill trigger).
//   Per-acc order (ci asc, ky, kx) unchanged -> bit-identical.
// MODE 0: +bias1, leaky_relu.  MODE 1: +bias2 +x residual.
template <int MODE>
__global__ __launch_bounds__(256) void conv3_k(
    const float* __restrict__ in, long ins,       // input planes, n-stride
    const float* __restrict__ Wt,                 // (64,64,3,3)
    const float* __restrict__ bias,
    const float* __restrict__ xfeats, int t,      // residual source (MODE 1)
    float* __restrict__ outf, long outs) {        // fp32 out planes, n-stride
  constexpr int TR = 16, TC = 32;      // output tile 16 rows x 32 cols
  constexpr int SR = 18, SC = 34;      // staged tile with halo
  constexpr int TS = 36;               // padded col stride (16B-aligned rows)
  constexpr int PL = SR * TS;          // 648 floats per ci plane
  constexpr int CI_STEP = 4;           // ci planes per round
  constexpr int HB = CI_STEP * PL;     // 2592 floats per buffer
  constexpr int NSTG = CI_STEP * SR * SC;   // 2448 staged elems per round
  __shared__ __align__(16) float tile[2 * HB];   // 20736 B total LDS

  const int tilex = blockIdx.x, tiley = blockIdx.y;   // 4 x 8 tiles
  const int n = blockIdx.z >> 3, cg = blockIdx.z & 7; // co-group of 8
  const int tid = threadIdx.x;
  const int wid = __builtin_amdgcn_readfirstlane(tid >> 6);  // 0..3, SGPR
  const int lane = tid & 63;
  const int prr = lane >> 3;           // 0..7 (2-row strips)
  const int pcc = lane & 7;            // 0..7 (4-col strips)
  const int coA = cg * 8 + wid;        // wave-uniform channels
  const int coB = coA + 4;

  const float* wpA = Wt + (long)coA * 576;   // s_load source (uniform)
  const float* wpB = Wt + (long)coB * 576;

  const float* inn = in + (long)n * ins;
  const int gy0 = tiley * TR - 1, gx0 = tilex * TC - 1;

  // ---- staging slots: 4 planes x 18x34 = 2448 elems over 256 threads ----
  int soff[10]; int slds[10]; bool sval[10]; bool sact[10];
  #pragma unroll
  for (int s = 0; s < 10; ++s) {
    int idx = tid + s * 256;
    sact[s] = idx < NSTG;
    int idc = sact[s] ? idx : 0;
    int cc = idc / (SR * SC); int rem = idc - cc * (SR * SC);
    int r = rem / SC;         int c = rem - r * SC;
    int gy = gy0 + r, gx = gx0 + c;
    bool inb = (gy >= 0) && (gy < H_) && (gx >= 0) && (gx < W_);
    sval[s] = sact[s] && inb;
    soff[s] = cc * HW_ + (inb ? (gy * W_ + gx) : 0);
    slds[s] = cc * PL + r * TS + c;
  }

  float acc[2][2][4];
  #pragma unroll
  for (int q = 0; q < 2; q++)
    #pragma unroll
    for (int i = 0; i < 2; i++)
      #pragma unroll
      for (int j = 0; j < 4; j++) acc[q][i][j] = 0.f;

  // ---- prologue: stage round 0 directly into buffer 0 ----
  #pragma unroll
  for (int s = 0; s < 10; ++s)
    if (sact[s]) tile[slds[s]] = sval[s] ? inn[soff[s]] : 0.f;
  __syncthreads();

  for (int rnd = 0; rnd < 16; ++rnd) {
    const int buf = rnd & 1;
    const bool more = rnd < 15;

    // issue next round's global loads FIRST: latency hides under compute
    float sreg[10];
    if (more) {
      const float* nb = inn + (long)(rnd + 1) * CI_STEP * HW_;
      #pragma unroll
      for (int s = 0; s < 10; ++s) sreg[s] = sval[s] ? nb[soff[s]] : 0.f;
    }

    const float* tb = tile + buf * HB;
    #pragma unroll
    for (int cc = 0; cc < CI_STEP; cc++) {
      const int ci = rnd * CI_STEP + cc;
      // weights: wave-uniform -> scalar loads (SMEM pipe, no LDS/VALU)
      float w0[9], w1[9];
      #pragma unroll
      for (int j = 0; j < 9; ++j) {
        w0[j] = wpA[ci * 9 + j];
        w1[j] = wpB[ci * 9 + j];
      }

      // input registers: 4 rows x 8 cols via 2x ds_read_b128 per row
      // (cols 6..7 over-read, unused; stay within padded TS=36 row)
      float vv[4][8];
      #pragma unroll
      for (int r = 0; r < 4; r++) {
        const float* tp = tb + cc * PL + (prr * 2 + r) * TS + pcc * 4;
        float4 a = *reinterpret_cast<const float4*>(tp);
        float4 b = *reinterpret_cast<const float4*>(tp + 4);
        vv[r][0] = a.x; vv[r][1] = a.y; vv[r][2] = a.z; vv[r][3] = a.w;
        vv[r][4] = b.x; vv[r][5] = b.y; vv[r][6] = b.z; vv[r][7] = b.w;
      }

      // 2 co x 2 oy x 4 ox x 9 taps per cc
      // (per-output order ci -> ky -> kx identical to all prior versions)
      #pragma unroll
      for (int oy = 0; oy < 2; oy++)
        #pragma unroll
        for (int ky = 0; ky < 3; ky++)
          #pragma unroll
          for (int kx = 0; kx < 3; kx++) {
            const float wA = w0[ky * 3 + kx];
            const float wB = w1[ky * 3 + kx];
            #pragma unroll
            for (int ox = 0; ox < 4; ox++) {
              float x = vv[oy + ky][ox + kx];
              acc[0][oy][ox] += wA * x;
              acc[1][oy][ox] += wB * x;
            }
          }
    }

    // write next round into the other buffer, then one barrier per round
    if (more) {
      float* db = tile + (1 - buf) * HB;
      #pragma unroll
      for (int s = 0; s < 10; ++s) if (sact[s]) db[slds[s]] = sreg[s];
    }
    __syncthreads();
  }

  // ---- epilogue: bias (+leaky | +residual), float4 stores ----
  const int py0 = tiley * TR + prr * 2, px0 = tilex * TC + pcc * 4;
  #pragma unroll
  for (int q = 0; q < 2; q++) {
    const int co = q ? coB : coA;
    const float bs = bias[co];
    float* ob = outf + (long)n * outs + (long)co * HW_;
    const float* xb = (MODE == 1)
        ? xfeats + (long)(n * T_ + t) * CHW_ + (long)co * HW_ : nullptr;
    #pragma unroll
    for (int oy = 0; oy < 2; oy++) {
      const long p = (long)(py0 + oy) * W_ + px0;
      float4 r;
      r.x = acc[q][oy][0] + bs;
      r.y = acc[q][oy][1] + bs;
      r.z = acc[q][oy][2] + bs;
      r.w = acc[q][oy][3] + bs;
      if (MODE == 0) {
        r.x = (r.x > 0.f) ? r.x : 0.1f * r.x;
        r.y = (r.y > 0.f) ? r.y : 0.1f * r.y;
        r.z = (r.z > 0.f) ? r.z : 0.1f * r.z;
        r.w = (r.w > 0.f) ? r.w : 0.1f * r.w;
      } else {
        float4 xres = *reinterpret_cast<const float4*>(&xb[p]);
        r.x += xres.x; r.y += xres.y; r.z += xres.z; r.w += xres.w;
      }
      *reinterpret_cast<float4*>(&ob[p]) = r;
    }
  }
}

extern "C" void kernel_launch(void* const* d_in, const int* in_sizes, int n_in,
                              void* d_out, int out_size, void* d_ws, size_t ws_size,
                              hipStream_t stream) {
  // Inputs fp32 AND output fp32 (reference returns jnp.float32; the test's
  // "(bf16, ...)" label is a hardcoded string).
  //
  // d_out planes (n,t) are the exact fp32 recurrent state: written at step t,
  // read as y1/y2 at steps t+1/t+2 (feats plane 0 for t<2). Scratch (infeat,
  // h1) -> d_ws if >=16 MiB, else dead feats/d_out planes (restore-per-launch
  // semantics make feats planes reusable once consumed).
  float* fmut = (float*)d_in[0];              // feats (2,16,64,128,128)
  const float* flows = (const float*)d_in[1]; // (2,16,2,128,128)
  const float* Wfc   = (const float*)d_in[2]; // (64,192)
  const float* bfc   = (const float*)d_in[3];
  const float* W1    = (const float*)d_in[4]; // (64,64,3,3)
  const float* b1v   = (const float*)d_in[5];
  const float* W2    = (const float*)d_in[6];
  const float* b2v   = (const float*)d_in[7];
  float* outF = (float*)d_out;                // (2,16,64,128,128) fp32

  const long FS = (long)T_ * CHW_;            // n-stride of feats/out (floats)
  float* ws = (float*)d_ws;
  const bool use_ws = ws_size >= (size_t)4 * CHW_ * sizeof(float);  // 16 MiB

  dim3 g3(4, 8, 16);
  for (int t = 0; t < T_; t++) {
    // ---- state sources (n-stride FS for both feats and out) ----
    const float* y1p = (t >= 1) ? outF + (long)(t - 1) * CHW_ : fmut;
    const float* y2p = (t >= 2) ? outF + (long)(t - 2) * CHW_ : fmut;

    // ---- scratch: infeat and h1 ----
    float *ifp, *h1p;
    long ifs, h1s;
    if (use_ws) {
      ifp = ws;                 ifs = CHW_;   // (N,C,H,W), 8 MiB
      h1p = ws + 2 * CHW_;      h1s = CHW_;   // 8 MiB
    } else {
      if (t == 0)      { ifp = outF + (long)14 * CHW_; ifs = FS; }
      else if (t == 1) { ifp = outF + (long)15 * CHW_; ifs = FS; }
      else             { ifp = fmut + (long)(t - 1) * CHW_; ifs = FS; }
      if (t == 0)      { h1p = outF + (long)15 * CHW_; h1s = FS; }
      else             { h1p = fmut; h1s = FS; }   // feats plane 0, dead for t>=1
    }

    warp_fc_k<<<512, 128, 0, stream>>>(
        flows, fmut, y1p, FS, y2p, FS, Wfc, bfc, t - 1, t - 2, t, ifp, ifs);
    conv3_k<0><<<g3, 256, 0, stream>>>(ifp, ifs, W1, b1v, nullptr, 0, h1p, h1s);
    conv3_k<1><<<g3, 256, 0, stream>>>(h1p, h1s, W2, b2v, fmut, t,
                                       outF + (long)t * CHW_, FS);
  }
}